// Round 5
// baseline (808.958 us; speedup 1.0000x reference)
//
#include <hip/hip_runtime.h>

#define TSEQ   2048
#define CDIM   2048
#define NHEAD  16
#define DHEAD  128
#define NBATCH 2
#define MROWS  (NBATCH * TSEQ)   // 4096
#define WIN    512

typedef unsigned short u16;
typedef __attribute__((ext_vector_type(8))) short short8;   // 8 bf16 (4 VGPRs)
typedef __attribute__((ext_vector_type(4))) float f32x4;
typedef __attribute__((ext_vector_type(16))) float f32x16;
typedef __attribute__((ext_vector_type(4))) u16 u16x4;
typedef __attribute__((ext_vector_type(8))) u16 u16x8;

__device__ __forceinline__ void gload_lds16(const void* g, void* l) {
  __builtin_amdgcn_global_load_lds(
      (const __attribute__((address_space(1))) unsigned int*)g,
      (__attribute__((address_space(3))) unsigned int*)l, 16, 0, 0);
}

__device__ __forceinline__ u16 f2bf(float f) {
  unsigned u = __float_as_uint(f);
  u += 0x7fffu + ((u >> 16) & 1u);   // RNE
  return (u16)(u >> 16);
}
__device__ __forceinline__ float bf2f(u16 h) {
  return __uint_as_float((unsigned)h << 16);
}

// ---------------------------------------------------------------------------
// Weight transpose + fp32->bf16 (z<4): WT[n*C + k] = bf16(W[k*C + n]).
// z==4 plane: bulk convert x fp32 -> bf16 (2 float4 per thread).
// ---------------------------------------------------------------------------
__global__ __launch_bounds__(256) void transpose_kernel(
    const float* __restrict__ i0, const float* __restrict__ i1,
    const float* __restrict__ i2, const float* __restrict__ i3,
    u16* __restrict__ o0, u16* __restrict__ o1,
    u16* __restrict__ o2, u16* __restrict__ o3,
    const float* __restrict__ xin, u16* __restrict__ xout) {
  const int z = blockIdx.z;
  if (z == 4) {
    const int tf = threadIdx.y * 32 + threadIdx.x;
    const int base = (blockIdx.y * 64 + blockIdx.x) * 512 + tf * 2;
#pragma unroll
    for (int c = 0; c < 2; ++c) {
      const float4 v = ((const float4*)xin)[base + c];
      u16x4 ov;
      ov[0] = f2bf(v.x); ov[1] = f2bf(v.y); ov[2] = f2bf(v.z); ov[3] = f2bf(v.w);
      ((u16x4*)xout)[base + c] = ov;
    }
    return;
  }
  const float* in = (z == 0) ? i0 : (z == 1) ? i1 : (z == 2) ? i2 : i3;
  u16*       out = (z == 0) ? o0 : (z == 1) ? o1 : (z == 2) ? o2 : o3;
  __shared__ u16 tile[32][33];
  const int x  = blockIdx.x * 32 + threadIdx.x;
  const int y0 = blockIdx.y * 32 + threadIdx.y;
#pragma unroll
  for (int i = 0; i < 32; i += 8)
    tile[threadIdx.y + i][threadIdx.x] = f2bf(in[(size_t)(y0 + i) * CDIM + x]);
  __syncthreads();
  const int x2 = blockIdx.y * 32 + threadIdx.x;
  const int y2 = blockIdx.x * 32 + threadIdx.y;
#pragma unroll
  for (int i = 0; i < 32; i += 8)
    out[(size_t)(y2 + i) * CDIM + x2] = tile[threadIdx.x][threadIdx.y + i];
}

// ---------------------------------------------------------------------------
// RoPE tables: ct/st[t*64 + i] = cos/sin(t * 10000^(-i/64))
// ---------------------------------------------------------------------------
__global__ __launch_bounds__(256) void rope_table_kernel(float* __restrict__ ct,
                                                         float* __restrict__ st) {
  const int idx = blockIdx.x * 256 + threadIdx.x;   // < TSEQ*64
  const int t = idx >> 6, i = idx & 63;
  const float inv = exp2f(-(float)i * (13.287712379549449f / 64.0f)); // log2(10000)/64
  const float f = (float)t * inv;
  ct[idx] = cosf(f);
  st[idx] = sinf(f);
}

// ---------------------------------------------------------------------------
// RoPE apply, in place on q (y=0) / k (y=1). rotate-half pairs (i, i+64).
// ---------------------------------------------------------------------------
__global__ __launch_bounds__(256) void rope_apply_kernel(
    u16* __restrict__ q, u16* __restrict__ k,
    const float* __restrict__ ct, const float* __restrict__ st) {
  const int flat = blockIdx.x * 256 + threadIdx.x;  // < B*T*H*64 = 2^22
  u16* X = (blockIdx.y == 0) ? q : k;
  const int i = flat & 63;
  const int h = (flat >> 6) & (NHEAD - 1);
  const int t = (flat >> 10) & (TSEQ - 1);
  const int b = flat >> 21;
  const size_t base = ((size_t)(b * TSEQ + t)) * CDIM + h * DHEAD + i;
  const float u1 = bf2f(X[base]), u2 = bf2f(X[base + 64]);
  const float c = ct[t * 64 + i], s = st[t * 64 + i];
  X[base]      = f2bf(u1 * c - u2 * s);
  X[base + 64] = f2bf(u1 * s + u2 * c);
}

// ---------------------------------------------------------------------------
// BK=64 GEMM: C[M=4096, N=2048] = A[M,K=2048] * Bt[N,K]^T, bf16 internal.
// 128x128 tile, 4 waves, 16x16x32 MFMA, global_load_lds width 16.
// XOR-swizzled LDS layout. Grid (n, z, m).
// Epilogues: OF!=null -> fp32 natural; z==vz -> bf16 vT; else bf16 natural.
// ---------------------------------------------------------------------------
__global__ __launch_bounds__(256, 4) void gemm_bt_kernel(
    const u16* __restrict__ A,
    const u16* __restrict__ B0, const u16* __restrict__ B1, const u16* __restrict__ B2,
    u16* __restrict__ O0, u16* __restrict__ O1, u16* __restrict__ O2,
    int vz, float* __restrict__ OF) {
  const int z = blockIdx.y;
  const u16* Bt = (z == 0) ? B0 : (z == 1) ? B1 : B2;
  u16*       O  = (z == 0) ? O0 : (z == 1) ? O1 : O2;

  __shared__ u16 As[128 * 64];   // 16 KB, swizzled row-major
  __shared__ u16 Bs[128 * 64];   // 16 KB

  const int tid  = threadIdx.x;
  const int wave = tid >> 6;
  const int lane = tid & 63;
  const int quad = lane >> 4;
  const int l15  = lane & 15;

  const int bm = blockIdx.z * 128;
  const int bn = blockIdx.x * 128;

  const int rlo = lane >> 3;                     // 0..7
  const int swb = ((lane & 7) + rlo) & 7;        // swizzled source block
  const u16* Ag = A  + (size_t)(bm + wave * 32 + rlo) * CDIM + swb * 8;
  const u16* Bg = Bt + (size_t)(bn + wave * 32 + rlo) * CDIM + swb * 8;
  u16* AsW = As + wave * 2048 + lane * 8;
  u16* BsW = Bs + wave * 2048 + lane * 8;

  const f32x4 zero4 = {0.f, 0.f, 0.f, 0.f};
  f32x4 acc[4][4];
#pragma unroll
  for (int mt = 0; mt < 4; ++mt)
#pragma unroll
    for (int nt = 0; nt < 4; ++nt) acc[mt][nt] = zero4;

  const int mh = (wave >> 1) * 64;
  const int nh = (wave & 1) * 64;

  const int off0 = ((quad - l15) & 7) * 8;       // ks = 0
  const int off1 = off0 ^ 32;                    // ks = 1

  for (int kb = 0; kb < CDIM; kb += 64) {
#pragma unroll
    for (int g = 0; g < 4; ++g) {
      gload_lds16(Ag + kb + (size_t)g * 8 * CDIM, AsW + g * 512);
      gload_lds16(Bg + kb + (size_t)g * 8 * CDIM, BsW + g * 512);
    }
    __syncthreads();

#pragma unroll
    for (int ks = 0; ks < 2; ++ks) {
      const int fo = ks ? off1 : off0;
      short8 af[4], bfr[4];
#pragma unroll
      for (int t = 0; t < 4; ++t) {
        af[t]  = *(const short8*)(As + (mh + t * 16 + l15) * 64 + fo);
        bfr[t] = *(const short8*)(Bs + (nh + t * 16 + l15) * 64 + fo);
      }
#pragma unroll
      for (int mt = 0; mt < 4; ++mt)
#pragma unroll
        for (int nt = 0; nt < 4; ++nt)
          acc[mt][nt] = __builtin_amdgcn_mfma_f32_16x16x32_bf16(af[mt], bfr[nt],
                                                                acc[mt][nt], 0, 0, 0);
    }
    __syncthreads();
  }

  if (OF != nullptr) {
#pragma unroll
    for (int mt = 0; mt < 4; ++mt) {
      const int row0 = bm + mh + mt * 16 + quad * 4;
#pragma unroll
      for (int nt = 0; nt < 4; ++nt) {
        const int col = bn + nh + nt * 16 + l15;
#pragma unroll
        for (int r = 0; r < 4; ++r)
          OF[(size_t)(row0 + r) * CDIM + col] = acc[mt][nt][r];
      }
    }
  } else if (z != vz) {
#pragma unroll
    for (int mt = 0; mt < 4; ++mt) {
      const int row0 = bm + mh + mt * 16 + quad * 4;
#pragma unroll
      for (int nt = 0; nt < 4; ++nt) {
        const int col = bn + nh + nt * 16 + l15;
#pragma unroll
        for (int r = 0; r < 4; ++r)
          O[(size_t)(row0 + r) * CDIM + col] = f2bf(acc[mt][nt][r]);
      }
    }
  } else {
    // v epilogue: O = vT[(b*H + head)*D + d][t]; packed 8B store
    const int head = bn >> 7;
#pragma unroll
    for (int mt = 0; mt < 4; ++mt) {
      const int gm0 = bm + mh + mt * 16 + quad * 4;
      const int b  = gm0 >> 11;
      const int t0 = gm0 & (TSEQ - 1);
#pragma unroll
      for (int nt = 0; nt < 4; ++nt) {
        const int d = nh + nt * 16 + l15;
        u16x4 pk;
#pragma unroll
        for (int r = 0; r < 4; ++r) pk[r] = f2bf(acc[mt][nt][r]);
        *(u16x4*)(O + ((size_t)((b * NHEAD + head) * DHEAD + d)) * TSEQ + t0) = pk;
      }
    }
  }
}

// ---------------------------------------------------------------------------
// Flash attention, S^T formulation, 32x32x16 MFMA, in-register softmax.
// R5: split-KV INSIDE the block. 512 threads = 8 waves; waves 0-3 (half 0)
// take the even-indexed active key tiles, waves 4-7 the odd ones, on
// separate LDS buffer pairs, sharing only the per-iteration barrier.
// Grid stays 512 -> 2 blocks/CU x 8 waves = 4 waves/SIMD (R2 had 2).
// Steps per block: ceil(nact/2) ~ 26-27 (R2: 52). Fixed-shift softmax makes
// (O,l) partials additive -> combine is a 64 KB LDS exchange at the end
// (half-1 writes O^T[d][q] fp32, [d][q32] layout = 2 lanes/bank; half-0
// adds, normalizes, stores bf16). ZERO extra HBM traffic vs R2 (R4's fp32
// global partials caused 625 MB fetch / L2 thrash -> reverted).
// Kept: XCD remap (K/V L2-resident), fixed V swizzle (conflicts 4x down).
// LDS 66 KB, 2 blocks/CU.
// ---------------------------------------------------------------------------
__global__ __launch_bounds__(512, 4) void attn_kernel(
    const u16* __restrict__ q, const u16* __restrict__ k,
    const u16* __restrict__ vT, u16* __restrict__ o) {
  // [ksA 8192][ksB 8192][vsA 8192][vsB 8192] u16 = 64 KB
  // (combine phase aliases the whole thing as float cb[4][128][32])
  __shared__ u16 smem[32768];
  __shared__ float lrLds[4 * 32];

  const int tid  = threadIdx.x;        // 0..511
  const int wave = tid >> 6;           // 0..7
  const int half = wave >> 2;          // 0 = even active tiles, 1 = odd
  const int w3   = wave & 3;           // wave within half-group
  const int lane = tid & 63;
  const int hi   = lane >> 5;          // k-half select in 32x32x16 fragments
  const int l31  = lane & 31;
  const int ht   = tid & 255;          // thread id within half-group

  // XCD-aware remap: xcd = flat%8 owns 4 heads x 16 q-blocks
  // -> 4 MB K/V working set per XCD = one L2.
  const int flat = blockIdx.y * 16 + blockIdx.x;   // [0,512)
  const int qb   = (flat >> 3) & 15;
  const int bh   = (flat & 7) * 4 + (flat >> 7);   // b*16 + h
  const int b    = bh >> 4;
  const int h    = bh & 15;
  const int qw0  = qb * 128 + w3 * 32;
  const int qi   = qw0 + l31;          // this lane's q row (col of S^T)

  u16* ksH = smem + half * 8192;            // [buf][key 32][chan 128]
  u16* vsH = smem + 16384 + half * 8192;    // [buf][d 128][key 32]

  // Q B-fragments: qf[s] = Q[qi][s*16 + hi*8 .. +8]
  short8 qf[8];
  {
    const u16* qrow = q + ((size_t)(b * TSEQ + qi)) * CDIM + h * DHEAD + hi * 8;
#pragma unroll
    for (int s = 0; s < 8; ++s) qf[s] = *(const short8*)(qrow + s * 16);
  }

  f32x16 oacc[4];   // [d-tile]: O^T[d = dt*32 + (reg&3)+8*(reg>>2)+4*hi][q = qi]
#pragma unroll
  for (int dt = 0; dt < 4; ++dt)
#pragma unroll
    for (int r = 0; r < 16; ++r) oacc[dt][r] = 0.f;
  float lrow = 0.f;

  const u16* kbase = k + ((size_t)(b * TSEQ)) * CDIM + h * DHEAD;
  const u16* vbase = vT + ((size_t)bh) * DHEAD * TSEQ;
  const float SC  = 0.08838834764831845f * 1.4426950408889634f; // 1/sqrt(128)*log2e
  const float MSH = 12.0f;   // fixed softmax shift (log2 domain)

  // remap out the fully-block-masked 32-key tiles: t in [4qb-12, 4qb-1]
  int tlo = 4 * qb - 12; if (tlo < 0) tlo = 0;
  int nskip = (4 * qb - 1) - tlo + 1; if (nskip < 0) nskip = 0;
  const int nact  = 64 - nskip;        // active tiles, >= 51
  const int nIter = (nact + 1) >> 1;   // barrier steps, ~26-32

  // active index a -> key tile; half takes a = 2*it + half
  auto jof = [&](int a) { return ((a < tlo) ? a : a + nskip) * 32; };

  // staging decomposition within the 256-thread half-group
  const int ki0 = ht >> 4, kc0 = ht & 15;   // k rows 0..15 (+16), 16 chunks
  const int vi0 = ht >> 2, vc0 = ht & 3;    // v rows 0..63 (+64), 4 chunks
  const int kswz = (kc0 ^ (ki0 & 7)) * 8;          // (ki0+16)&7 == ki0&7
  const int vswz = (vc0 ^ ((vi0 >> 2) & 3)) * 8;   // ((vi0+64)>>2)&3 == (vi0>>2)&3

  auto loadT = [&](int j, u16x8& a, u16x8& c2, u16x8& d, u16x8& e) {
    a  = *(const u16x8*)(kbase + (size_t)(j + ki0) * CDIM + kc0 * 8);
    c2 = *(const u16x8*)(kbase + (size_t)(j + ki0 + 16) * CDIM + kc0 * 8);
    d  = *(const u16x8*)(vbase + (size_t)vi0 * TSEQ + j + vc0 * 8);
    e  = *(const u16x8*)(vbase + (size_t)(vi0 + 64) * TSEQ + j + vc0 * 8);
  };
  auto writeT = [&](int buf, const u16x8& a, const u16x8& c2,
                    const u16x8& d, const u16x8& e) {
    u16* ksn = ksH + buf * (32 * 128);
    u16* vsn = vsH + buf * (128 * 32);
    *(u16x8*)(ksn + ki0 * 128 + kswz) = a;
    *(u16x8*)(ksn + (ki0 + 16) * 128 + kswz) = c2;
    *(u16x8*)(vsn + vi0 * 32 + vswz) = d;
    *(u16x8*)(vsn + (vi0 + 64) * 32 + vswz) = e;
  };

  u16x8 pk0, pk1, pv0, pv1;
  // prologue: stage tile a=half into buffer 0 (a=half < nact always)
  loadT(jof(half), pk0, pk1, pv0, pv1);
  writeT(0, pk0, pk1, pv0, pv1);
  __syncthreads();

  for (int it = 0; it < nIter; ++it) {
    const int p  = it & 1;
    const int a  = 2 * it + half;
    const int an = a + 2;
    const bool va = a < nact;
    const bool vn = an < nact;

    // issue next tile's global loads (latency hidden by compute below)
    if (vn) loadT(jof(an), pk0, pk1, pv0, pv1);

    const u16* ksp = ksH + p * (32 * 128);
    const u16* vsp = vsH + p * (128 * 32);

    if (va) {
      const int j0 = jof(a);
      const bool wskip = (j0 + 31 <= qw0) && (j0 >= qw0 + 31 - (WIN - 1));
      if (!wskip) {
        // S^T = K * Q^T: one 32x32 tile, K=128 over 8 MFMAs.
        f32x16 sf;
#pragma unroll
        for (int r = 0; r < 16; ++r) sf[r] = 0.f;
#pragma unroll
        for (int s = 0; s < 8; ++s) {
          const short8 kf =
              *(const short8*)(ksp + l31 * 128 + (((s * 2 + hi) ^ (l31 & 7)) * 8));
          sf = __builtin_amdgcn_mfma_f32_32x32x16_bf16(kf, qf[s], sf, 0, 0, 0);
        }

        // softmax numerator (+ mask only on band-edge tiles, wave-uniform).
        // element r: key = j0 + (r&3) + 8*(r>>2) + 4*hi, q = qi.
        float pe[16];
        const bool hasMask = (qw0 + 31 >= j0) && (qw0 <= j0 + 31 + (WIN - 1));
        if (hasMask) {
#pragma unroll
          for (int r = 0; r < 16; ++r) {
            const int kj = j0 + (r & 3) + 8 * (r >> 2) + 4 * hi;
            const float e = exp2f(fmaf(sf[r], SC, -MSH));
            pe[r] = ((unsigned)(qi - kj) < (unsigned)WIN) ? 0.f : e;
          }
        } else {
#pragma unroll
          for (int r = 0; r < 16; ++r) pe[r] = exp2f(fmaf(sf[r], SC, -MSH));
        }
#pragma unroll
        for (int r = 0; r < 16; ++r) lrow += pe[r];

        // P -> bf16 PV B-fragments, fully in registers:
        // 8x v_cvt_pk_bf16_f32 + 4x v_permlane32_swap_b32.
        int D0, D1, D2, D3, D4, D5, D6, D7;
        asm("v_cvt_pk_bf16_f32 %0, %1, %2" : "=v"(D0) : "v"(pe[0]),  "v"(pe[1]));
        asm("v_cvt_pk_bf16_f32 %0, %1, %2" : "=v"(D1) : "v"(pe[2]),  "v"(pe[3]));
        asm("v_cvt_pk_bf16_f32 %0, %1, %2" : "=v"(D2) : "v"(pe[4]),  "v"(pe[5]));
        asm("v_cvt_pk_bf16_f32 %0, %1, %2" : "=v"(D3) : "v"(pe[6]),  "v"(pe[7]));
        asm("v_cvt_pk_bf16_f32 %0, %1, %2" : "=v"(D4) : "v"(pe[8]),  "v"(pe[9]));
        asm("v_cvt_pk_bf16_f32 %0, %1, %2" : "=v"(D5) : "v"(pe[10]), "v"(pe[11]));
        asm("v_cvt_pk_bf16_f32 %0, %1, %2" : "=v"(D6) : "v"(pe[12]), "v"(pe[13]));
        asm("v_cvt_pk_bf16_f32 %0, %1, %2" : "=v"(D7) : "v"(pe[14]), "v"(pe[15]));
        asm("v_permlane32_swap_b32 %0, %1" : "+v"(D0), "+v"(D2));
        asm("v_permlane32_swap_b32 %0, %1" : "+v"(D1), "+v"(D3));
        asm("v_permlane32_swap_b32 %0, %1" : "+v"(D4), "+v"(D6));
        asm("v_permlane32_swap_b32 %0, %1" : "+v"(D5), "+v"(D7));

        union { int i[4]; short8 s8; } u0, u1;
        u0.i[0] = D0; u0.i[1] = D1; u0.i[2] = D2; u0.i[3] = D3;
        u1.i[0] = D4; u1.i[1] = D5; u1.i[2] = D6; u1.i[3] = D7;
        const short8 pf0 = u0.s8;   // B[k = keys 0..15][q]
        const short8 pf1 = u1.s8;   // B[k = keys 16..31][q]

        // O^T += V^T * P^T  (A = V^T rows d, 4 d-tiles x 2 k-steps)
#pragma unroll
        for (int dt = 0; dt < 4; ++dt) {
          const int row = dt * 32 + l31;
          const short8 vf0 =
              *(const short8*)(vsp + row * 32 + (((0 + hi) ^ ((l31 >> 2) & 3)) * 8));
          const short8 vf1 =
              *(const short8*)(vsp + row * 32 + (((2 + hi) ^ ((l31 >> 2) & 3)) * 8));
          oacc[dt] = __builtin_amdgcn_mfma_f32_32x32x16_bf16(vf0, pf0, oacc[dt], 0, 0, 0);
          oacc[dt] = __builtin_amdgcn_mfma_f32_32x32x16_bf16(vf1, pf1, oacc[dt], 0, 0, 0);
        }
      }
    }

    // write prefetched tile to the other buffer (loads have landed by now)
    if (vn) writeT(1 - p, pk0, pk1, pv0, pv1);
    __syncthreads();
  }

  // lrow: lanes hi=0/1 hold complementary key subsets for the same q
  lrow += __shfl_xor(lrow, 32, 64);

  // combine the two halves through LDS (aliases the staging buffers; all
  // tile reads completed at the loop's final barrier).
  float* cb = (float*)smem;   // [w3][d 128][q 32] fp32 = 64 KB
  if (half == 1) {
    if (hi == 0) lrLds[w3 * 32 + l31] = lrow;
#pragma unroll
    for (int dt = 0; dt < 4; ++dt)
#pragma unroll
      for (int r = 0; r < 16; ++r) {
        const int d = dt * 32 + 8 * (r >> 2) + 4 * hi + (r & 3);
        cb[((w3 << 7) + d) * 32 + l31] = oacc[dt][r];
      }
  }
  __syncthreads();
  if (half == 0) {
    const float inv = 1.0f / (lrow + lrLds[w3 * 32 + l31]);
    u16* obase = o + ((size_t)(b * TSEQ + qi)) * CDIM + h * DHEAD;
#pragma unroll
    for (int dt = 0; dt < 4; ++dt)
#pragma unroll
      for (int a2 = 0; a2 < 4; ++a2) {
        u16x4 pkd;
#pragma unroll
        for (int rr = 0; rr < 4; ++rr) {
          const int d = dt * 32 + 8 * a2 + 4 * hi + rr;
          const float v = oacc[dt][a2 * 4 + rr] + cb[((w3 << 7) + d) * 32 + l31];
          pkd[rr] = f2bf(v * inv);
        }
        *(u16x4*)(obase + dt * 32 + a2 * 8 + hi * 4) = pkd;
      }
  }
}

// ---------------------------------------------------------------------------
extern "C" void kernel_launch(void* const* d_in, const int* in_sizes, int n_in,
                              void* d_out, int out_size, void* d_ws, size_t ws_size,
                              hipStream_t stream) {
  (void)in_sizes; (void)n_in; (void)out_size; (void)ws_size;
  const float* x  = (const float*)d_in[0];
  const float* Wq = (const float*)d_in[1];
  const float* Wk = (const float*)d_in[2];
  const float* Wv = (const float*)d_in[3];
  const float* Wo = (const float*)d_in[4];
  float* out = (float*)d_out;

  char* ws = (char*)d_ws;
  const size_t WT = (size_t)CDIM * CDIM * sizeof(u16);   // 8 MiB
  const size_t QS = (size_t)MROWS * CDIM * sizeof(u16);  // 16 MiB
  u16* WqT = (u16*)(ws + 0 * WT);
  u16* WkT = (u16*)(ws + 1 * WT);
  u16* WvT = (u16*)(ws + 2 * WT);
  u16* WoT = (u16*)(ws + 3 * WT);
  u16* xb  = (u16*)(ws + 4 * WT);
  u16* qb  = (u16*)(ws + 4 * WT + 1 * QS);
  u16* kb  = (u16*)(ws + 4 * WT + 2 * QS);
  u16* vTb = (u16*)(ws + 4 * WT + 3 * QS);
  u16* ob  = (u16*)(ws + 4 * WT + 4 * QS);
  float* ct = (float*)(ws + 4 * WT + 5 * QS);
  float* st = ct + TSEQ * 64;

  transpose_kernel<<<dim3(64, 64, 5), dim3(32, 8), 0, stream>>>(
      Wq, Wk, Wv, Wo, WqT, WkT, WvT, WoT, x, xb);
  rope_table_kernel<<<dim3(TSEQ * 64 / 256), 256, 0, stream>>>(ct, st);
  gemm_bt_kernel<<<dim3(16, 3, 32), 256, 0, stream>>>(
      xb, WqT, WkT, WvT, qb, kb, vTb, 2, nullptr);
  rope_apply_kernel<<<dim3(16384, 2), 256, 0, stream>>>(qb, kb, ct, st);
  attn_kernel<<<dim3(16, 32), 512, 0, stream>>>(qb, kb, vTb, ob);
  gemm_bt_kernel<<<dim3(16, 1, 32), 256, 0, stream>>>(
      ob, WoT, WoT, WoT, nullptr, nullptr, nullptr, -1, out);
}

// Round 6
// 437.771 us; speedup vs baseline: 1.8479x; 1.8479x over previous
//
#include <hip/hip_runtime.h>

#define TSEQ   2048
#define CDIM   2048
#define NHEAD  16
#define DHEAD  128
#define NBATCH 2
#define MROWS  (NBATCH * TSEQ)   // 4096
#define WIN    512

typedef unsigned short u16;
typedef __attribute__((ext_vector_type(8))) short short8;   // 8 bf16 (4 VGPRs)
typedef __attribute__((ext_vector_type(4))) float f32x4;
typedef __attribute__((ext_vector_type(16))) float f32x16;
typedef __attribute__((ext_vector_type(4))) u16 u16x4;
typedef __attribute__((ext_vector_type(8))) u16 u16x8;

__device__ __forceinline__ void gload_lds16(const void* g, void* l) {
  __builtin_amdgcn_global_load_lds(
      (const __attribute__((address_space(1))) unsigned int*)g,
      (__attribute__((address_space(3))) unsigned int*)l, 16, 0, 0);
}

__device__ __forceinline__ u16 f2bf(float f) {
  unsigned u = __float_as_uint(f);
  u += 0x7fffu + ((u >> 16) & 1u);   // RNE
  return (u16)(u >> 16);
}
__device__ __forceinline__ float bf2f(u16 h) {
  return __uint_as_float((unsigned)h << 16);
}

// ---------------------------------------------------------------------------
// Weight transpose + fp32->bf16 (z<4): WT[n*C + k] = bf16(W[k*C + n]).
// z==4 plane: bulk convert x fp32 -> bf16 (2 float4 per thread).
// ---------------------------------------------------------------------------
__global__ __launch_bounds__(256) void transpose_kernel(
    const float* __restrict__ i0, const float* __restrict__ i1,
    const float* __restrict__ i2, const float* __restrict__ i3,
    u16* __restrict__ o0, u16* __restrict__ o1,
    u16* __restrict__ o2, u16* __restrict__ o3,
    const float* __restrict__ xin, u16* __restrict__ xout) {
  const int z = blockIdx.z;
  if (z == 4) {
    const int tf = threadIdx.y * 32 + threadIdx.x;
    const int base = (blockIdx.y * 64 + blockIdx.x) * 512 + tf * 2;
#pragma unroll
    for (int c = 0; c < 2; ++c) {
      const float4 v = ((const float4*)xin)[base + c];
      u16x4 ov;
      ov[0] = f2bf(v.x); ov[1] = f2bf(v.y); ov[2] = f2bf(v.z); ov[3] = f2bf(v.w);
      ((u16x4*)xout)[base + c] = ov;
    }
    return;
  }
  const float* in = (z == 0) ? i0 : (z == 1) ? i1 : (z == 2) ? i2 : i3;
  u16*       out = (z == 0) ? o0 : (z == 1) ? o1 : (z == 2) ? o2 : o3;
  __shared__ u16 tile[32][33];
  const int x  = blockIdx.x * 32 + threadIdx.x;
  const int y0 = blockIdx.y * 32 + threadIdx.y;
#pragma unroll
  for (int i = 0; i < 32; i += 8)
    tile[threadIdx.y + i][threadIdx.x] = f2bf(in[(size_t)(y0 + i) * CDIM + x]);
  __syncthreads();
  const int x2 = blockIdx.y * 32 + threadIdx.x;
  const int y2 = blockIdx.x * 32 + threadIdx.y;
#pragma unroll
  for (int i = 0; i < 32; i += 8)
    out[(size_t)(y2 + i) * CDIM + x2] = tile[threadIdx.x][threadIdx.y + i];
}

// ---------------------------------------------------------------------------
// RoPE tables: ct/st[t*64 + i] = cos/sin(t * 10000^(-i/64))
// ---------------------------------------------------------------------------
__global__ __launch_bounds__(256) void rope_table_kernel(float* __restrict__ ct,
                                                         float* __restrict__ st) {
  const int idx = blockIdx.x * 256 + threadIdx.x;   // < TSEQ*64
  const int t = idx >> 6, i = idx & 63;
  const float inv = exp2f(-(float)i * (13.287712379549449f / 64.0f)); // log2(10000)/64
  const float f = (float)t * inv;
  ct[idx] = cosf(f);
  st[idx] = sinf(f);
}

// ---------------------------------------------------------------------------
// RoPE apply, in place on q (y=0) / k (y=1). rotate-half pairs (i, i+64).
// ---------------------------------------------------------------------------
__global__ __launch_bounds__(256) void rope_apply_kernel(
    u16* __restrict__ q, u16* __restrict__ k,
    const float* __restrict__ ct, const float* __restrict__ st) {
  const int flat = blockIdx.x * 256 + threadIdx.x;  // < B*T*H*64 = 2^22
  u16* X = (blockIdx.y == 0) ? q : k;
  const int i = flat & 63;
  const int h = (flat >> 6) & (NHEAD - 1);
  const int t = (flat >> 10) & (TSEQ - 1);
  const int b = flat >> 21;
  const size_t base = ((size_t)(b * TSEQ + t)) * CDIM + h * DHEAD + i;
  const float u1 = bf2f(X[base]), u2 = bf2f(X[base + 64]);
  const float c = ct[t * 64 + i], s = st[t * 64 + i];
  X[base]      = f2bf(u1 * c - u2 * s);
  X[base + 64] = f2bf(u1 * s + u2 * c);
}

// ---------------------------------------------------------------------------
// BK=64 GEMM: C[M=4096, N=2048] = A[M,K=2048] * Bt[N,K]^T, bf16 internal.
// 128x128 tile, 4 waves, 16x16x32 MFMA, global_load_lds width 16.
// XOR-swizzled LDS layout. Grid (n, z, m).
// Epilogues: OF!=null -> fp32 natural; z==vz -> bf16 vT; else bf16 natural.
// ---------------------------------------------------------------------------
__global__ __launch_bounds__(256, 4) void gemm_bt_kernel(
    const u16* __restrict__ A,
    const u16* __restrict__ B0, const u16* __restrict__ B1, const u16* __restrict__ B2,
    u16* __restrict__ O0, u16* __restrict__ O1, u16* __restrict__ O2,
    int vz, float* __restrict__ OF) {
  const int z = blockIdx.y;
  const u16* Bt = (z == 0) ? B0 : (z == 1) ? B1 : B2;
  u16*       O  = (z == 0) ? O0 : (z == 1) ? O1 : O2;

  __shared__ u16 As[128 * 64];   // 16 KB, swizzled row-major
  __shared__ u16 Bs[128 * 64];   // 16 KB

  const int tid  = threadIdx.x;
  const int wave = tid >> 6;
  const int lane = tid & 63;
  const int quad = lane >> 4;
  const int l15  = lane & 15;

  const int bm = blockIdx.z * 128;
  const int bn = blockIdx.x * 128;

  const int rlo = lane >> 3;                     // 0..7
  const int swb = ((lane & 7) + rlo) & 7;        // swizzled source block
  const u16* Ag = A  + (size_t)(bm + wave * 32 + rlo) * CDIM + swb * 8;
  const u16* Bg = Bt + (size_t)(bn + wave * 32 + rlo) * CDIM + swb * 8;
  u16* AsW = As + wave * 2048 + lane * 8;
  u16* BsW = Bs + wave * 2048 + lane * 8;

  const f32x4 zero4 = {0.f, 0.f, 0.f, 0.f};
  f32x4 acc[4][4];
#pragma unroll
  for (int mt = 0; mt < 4; ++mt)
#pragma unroll
    for (int nt = 0; nt < 4; ++nt) acc[mt][nt] = zero4;

  const int mh = (wave >> 1) * 64;
  const int nh = (wave & 1) * 64;

  const int off0 = ((quad - l15) & 7) * 8;       // ks = 0
  const int off1 = off0 ^ 32;                    // ks = 1

  for (int kb = 0; kb < CDIM; kb += 64) {
#pragma unroll
    for (int g = 0; g < 4; ++g) {
      gload_lds16(Ag + kb + (size_t)g * 8 * CDIM, AsW + g * 512);
      gload_lds16(Bg + kb + (size_t)g * 8 * CDIM, BsW + g * 512);
    }
    __syncthreads();

#pragma unroll
    for (int ks = 0; ks < 2; ++ks) {
      const int fo = ks ? off1 : off0;
      short8 af[4], bfr[4];
#pragma unroll
      for (int t = 0; t < 4; ++t) {
        af[t]  = *(const short8*)(As + (mh + t * 16 + l15) * 64 + fo);
        bfr[t] = *(const short8*)(Bs + (nh + t * 16 + l15) * 64 + fo);
      }
#pragma unroll
      for (int mt = 0; mt < 4; ++mt)
#pragma unroll
        for (int nt = 0; nt < 4; ++nt)
          acc[mt][nt] = __builtin_amdgcn_mfma_f32_16x16x32_bf16(af[mt], bfr[nt],
                                                                acc[mt][nt], 0, 0, 0);
    }
    __syncthreads();
  }

  if (OF != nullptr) {
#pragma unroll
    for (int mt = 0; mt < 4; ++mt) {
      const int row0 = bm + mh + mt * 16 + quad * 4;
#pragma unroll
      for (int nt = 0; nt < 4; ++nt) {
        const int col = bn + nh + nt * 16 + l15;
#pragma unroll
        for (int r = 0; r < 4; ++r)
          OF[(size_t)(row0 + r) * CDIM + col] = acc[mt][nt][r];
      }
    }
  } else if (z != vz) {
#pragma unroll
    for (int mt = 0; mt < 4; ++mt) {
      const int row0 = bm + mh + mt * 16 + quad * 4;
#pragma unroll
      for (int nt = 0; nt < 4; ++nt) {
        const int col = bn + nh + nt * 16 + l15;
#pragma unroll
        for (int r = 0; r < 4; ++r)
          O[(size_t)(row0 + r) * CDIM + col] = f2bf(acc[mt][nt][r]);
      }
    }
  } else {
    // v epilogue: O = vT[(b*H + head)*D + d][t]; packed 8B store
    const int head = bn >> 7;
#pragma unroll
    for (int mt = 0; mt < 4; ++mt) {
      const int gm0 = bm + mh + mt * 16 + quad * 4;
      const int b  = gm0 >> 11;
      const int t0 = gm0 & (TSEQ - 1);
#pragma unroll
      for (int nt = 0; nt < 4; ++nt) {
        const int d = nh + nt * 16 + l15;
        u16x4 pk;
#pragma unroll
        for (int r = 0; r < 4; ++r) pk[r] = f2bf(acc[mt][nt][r]);
        *(u16x4*)(O + ((size_t)((b * NHEAD + head) * DHEAD + d)) * TSEQ + t0) = pk;
      }
    }
  }
}

// ---------------------------------------------------------------------------
// Flash attention, S^T formulation, 32x32x16 MFMA, in-register softmax.
// R6: 8 waves/block (512 thr), d-SPLIT: wave (w3, wd) owns q-subtile w3
// (32 rows) and d-half wd (64 of 128 channels). Waves w and w+4 duplicate
// the 8-MFMA QK^T (S^T identical) but each does half the PV (4 MFMAs) and
// holds HALF the accumulator (oacc[2] = 32 regs). Per-wave unified-file
// budget: 32 acc + 32 qf + ~35 transients + addr ~= 115 < 128 -> fits the
// 4-waves/SIMD cap WITHOUT spilling (R4/R5 failure: launch_bounds(,4) with
// 64-reg oacc forced ~80 spilled regs -> 2 GB scratch traffic).
// Staging via global_load_lds with PRE-SWIZZLED per-lane global source
// (LDS dest linear; reads apply the same XOR): no staging registers, no
// writeT phase; one K + one V gload per wave per tile. All 8 waves share
// one 16 KB K/V tile pair, double-buffered = 32 KB LDS.
// No partials, no combine: each wave computes full lrow, writes its own
// 64 d-channels. Grid 512 = 2 blocks/CU = 4 waves/SIMD.
// Kept: XCD remap (K/V L2-resident), R2 V-swizzle, tile-skip remap.
// ---------------------------------------------------------------------------
__global__ __launch_bounds__(512, 4) void attn_kernel(
    const u16* __restrict__ q, const u16* __restrict__ k,
    const u16* __restrict__ vT, u16* __restrict__ o) {
  __shared__ u16 ks[2 * 32 * 128];   // [buf][key 32][chan 128], chunk-swizzled
  __shared__ u16 vs[2 * 128 * 32];   // [buf][d 128][key 32], chunk-swizzled

  const int tid  = threadIdx.x;        // 0..511
  const int wave = tid >> 6;           // 0..7
  const int w3   = wave & 3;           // q-subtile
  const int wd   = wave >> 2;          // d-half: 0 -> d 0..63, 1 -> d 64..127
  const int lane = tid & 63;
  const int hi   = lane >> 5;          // k-half select in 32x32x16 fragments
  const int l31  = lane & 31;

  // XCD-aware remap: xcd = flat%8 owns 4 heads x 16 q-blocks
  // -> 4 MB K/V working set per XCD = one L2.
  const int flat = blockIdx.y * 16 + blockIdx.x;   // [0,512)
  const int qb   = (flat >> 3) & 15;
  const int bh   = (flat & 7) * 4 + (flat >> 7);   // b*16 + h
  const int b    = bh >> 4;
  const int h    = bh & 15;
  const int qw0  = qb * 128 + w3 * 32;
  const int qi   = qw0 + l31;          // this lane's q row (col of S^T)

  // Q B-fragments: qf[s] = Q[qi][s*16 + hi*8 .. +8]
  short8 qf[8];
  {
    const u16* qrow = q + ((size_t)(b * TSEQ + qi)) * CDIM + h * DHEAD + hi * 8;
#pragma unroll
    for (int s = 0; s < 8; ++s) qf[s] = *(const short8*)(qrow + s * 16);
  }

  f32x16 oacc[2];   // [dt]: O^T[d = wd*64 + dt*32 + (r&3)+8*(r>>2)+4*hi][q = qi]
#pragma unroll
  for (int dt = 0; dt < 2; ++dt)
#pragma unroll
    for (int r = 0; r < 16; ++r) oacc[dt][r] = 0.f;
  float lrow = 0.f;

  const u16* kbase = k + ((size_t)(b * TSEQ)) * CDIM + h * DHEAD;
  const u16* vbase = vT + ((size_t)bh) * DHEAD * TSEQ;
  const float SC  = 0.08838834764831845f * 1.4426950408889634f; // 1/sqrt(128)*log2e
  const float MSH = 12.0f;   // fixed softmax shift (log2 domain)

  // remap out the fully-block-masked 32-key tiles: t in [4qb-12, 4qb-1]
  int tlo = 4 * qb - 12; if (tlo < 0) tlo = 0;
  int nskip = (4 * qb - 1) - tlo + 1; if (nskip < 0) nskip = 0;
  const int nact = 64 - nskip;   // 52..64
  auto jof = [&](int a) { return ((a < tlo) ? a : a + nskip) * 32; };

  // gload_lds staging: wave w stages 1 KB of K and 1 KB of V per tile.
  // LDS dest linear (base + lane*16); global SOURCE pre-swizzled so that
  // LDS[row][c] = K[row][c ^ (row&7)] (16B chunks), matching the reads.
  const int krow = 4 * wave + (lane >> 4);             // K row 0..31
  const int kc   = lane & 15;                          // 16B chunk 0..15
  const u16* kgp = kbase + (size_t)krow * CDIM + ((kc ^ (krow & 7)) * 8);
  const int vrow = 16 * wave + (lane >> 2);            // V row (d) 0..127
  const int vc   = lane & 3;                           // 16B chunk 0..3
  const u16* vgp = vbase + (size_t)vrow * TSEQ + ((vc ^ ((vrow >> 2) & 3)) * 8);
  u16* ksw = ks + wave * 512 + lane * 8;               // buf0; buf1 = +4096
  u16* vsw = vs + wave * 512 + lane * 8;

  // prologue: stage tile 0 into buffer 0
  {
    const int j00 = jof(0);
    gload_lds16(kgp + (size_t)j00 * CDIM, ksw);
    gload_lds16(vgp + j00, vsw);
  }
  __syncthreads();

  for (int it = 0; it < nact; ++it) {
    const int p = it & 1;
    const int j0 = jof(it);

    // issue next tile's gloads into the other buffer (hidden under compute;
    // the barrier at loop end drains vmcnt before anyone reads it)
    if (it + 1 < nact) {
      const int jn = jof(it + 1);
      gload_lds16(kgp + (size_t)jn * CDIM, ksw + (1 - p) * 4096);
      gload_lds16(vgp + jn, vsw + (1 - p) * 4096);
    }

    const u16* ksp = ks + p * 4096;
    const u16* vsp = vs + p * 4096;

    const bool wskip = (j0 + 31 <= qw0) && (j0 >= qw0 + 31 - (WIN - 1));
    if (!wskip) {
      // S^T = K * Q^T: one 32x32 tile, K=128 over 8 MFMAs (dup across wd).
      f32x16 sf;
#pragma unroll
      for (int r = 0; r < 16; ++r) sf[r] = 0.f;
#pragma unroll
      for (int s = 0; s < 8; ++s) {
        const short8 kf =
            *(const short8*)(ksp + l31 * 128 + (((s * 2 + hi) ^ (l31 & 7)) * 8));
        sf = __builtin_amdgcn_mfma_f32_32x32x16_bf16(kf, qf[s], sf, 0, 0, 0);
      }

      // softmax numerator (+ mask only on band-edge tiles, wave-uniform).
      // element r: key = j0 + (r&3) + 8*(r>>2) + 4*hi, q = qi.
      float pe[16];
      const bool hasMask = (qw0 + 31 >= j0) && (qw0 <= j0 + 31 + (WIN - 1));
      if (hasMask) {
#pragma unroll
        for (int r = 0; r < 16; ++r) {
          const int kj = j0 + (r & 3) + 8 * (r >> 2) + 4 * hi;
          const float e = exp2f(fmaf(sf[r], SC, -MSH));
          pe[r] = ((unsigned)(qi - kj) < (unsigned)WIN) ? 0.f : e;
        }
      } else {
#pragma unroll
        for (int r = 0; r < 16; ++r) pe[r] = exp2f(fmaf(sf[r], SC, -MSH));
      }
#pragma unroll
      for (int r = 0; r < 16; ++r) lrow += pe[r];

      // P -> bf16 PV B-fragments, fully in registers:
      // 8x v_cvt_pk_bf16_f32 + 4x v_permlane32_swap_b32.
      int D0, D1, D2, D3, D4, D5, D6, D7;
      asm("v_cvt_pk_bf16_f32 %0, %1, %2" : "=v"(D0) : "v"(pe[0]),  "v"(pe[1]));
      asm("v_cvt_pk_bf16_f32 %0, %1, %2" : "=v"(D1) : "v"(pe[2]),  "v"(pe[3]));
      asm("v_cvt_pk_bf16_f32 %0, %1, %2" : "=v"(D2) : "v"(pe[4]),  "v"(pe[5]));
      asm("v_cvt_pk_bf16_f32 %0, %1, %2" : "=v"(D3) : "v"(pe[6]),  "v"(pe[7]));
      asm("v_cvt_pk_bf16_f32 %0, %1, %2" : "=v"(D4) : "v"(pe[8]),  "v"(pe[9]));
      asm("v_cvt_pk_bf16_f32 %0, %1, %2" : "=v"(D5) : "v"(pe[10]), "v"(pe[11]));
      asm("v_cvt_pk_bf16_f32 %0, %1, %2" : "=v"(D6) : "v"(pe[12]), "v"(pe[13]));
      asm("v_cvt_pk_bf16_f32 %0, %1, %2" : "=v"(D7) : "v"(pe[14]), "v"(pe[15]));
      asm("v_permlane32_swap_b32 %0, %1" : "+v"(D0), "+v"(D2));
      asm("v_permlane32_swap_b32 %0, %1" : "+v"(D1), "+v"(D3));
      asm("v_permlane32_swap_b32 %0, %1" : "+v"(D4), "+v"(D6));
      asm("v_permlane32_swap_b32 %0, %1" : "+v"(D5), "+v"(D7));

      union { int i[4]; short8 s8; } u0, u1;
      u0.i[0] = D0; u0.i[1] = D1; u0.i[2] = D2; u0.i[3] = D3;
      u1.i[0] = D4; u1.i[1] = D5; u1.i[2] = D6; u1.i[3] = D7;
      const short8 pf0 = u0.s8;   // B[k = keys 0..15][q]
      const short8 pf1 = u1.s8;   // B[k = keys 16..31][q]

      // O^T += V^T * P^T  (A = V^T rows d; this wave: 2 d-tiles x 2 k-steps)
#pragma unroll
      for (int dt = 0; dt < 2; ++dt) {
        const int row = wd * 64 + dt * 32 + l31;
        const short8 vf0 =
            *(const short8*)(vsp + row * 32 + (((0 + hi) ^ ((l31 >> 2) & 3)) * 8));
        const short8 vf1 =
            *(const short8*)(vsp + row * 32 + (((2 + hi) ^ ((l31 >> 2) & 3)) * 8));
        oacc[dt] = __builtin_amdgcn_mfma_f32_32x32x16_bf16(vf0, pf0, oacc[dt], 0, 0, 0);
        oacc[dt] = __builtin_amdgcn_mfma_f32_32x32x16_bf16(vf1, pf1, oacc[dt], 0, 0, 0);
      }
    }

    __syncthreads();   // drains vmcnt (prefetch landed) + frees buf p
  }

  // lrow: lanes hi=0/1 hold complementary key subsets for the same q
  lrow += __shfl_xor(lrow, 32, 64);
  const float inv = 1.0f / lrow;

  // O^T[d][q]: reg r of tile dt -> d = wd*64 + dt*32 + 8*(r>>2) + 4*hi + (r&3)
  u16* obase = o + ((size_t)(b * TSEQ + qi)) * CDIM + h * DHEAD + wd * 64;
#pragma unroll
  for (int dt = 0; dt < 2; ++dt)
#pragma unroll
    for (int a2 = 0; a2 < 4; ++a2) {
      u16x4 pkd;
#pragma unroll
      for (int r = 0; r < 4; ++r) pkd[r] = f2bf(oacc[dt][a2 * 4 + r] * inv);
      *(u16x4*)(obase + dt * 32 + a2 * 8 + hi * 4) = pkd;
    }
}

// ---------------------------------------------------------------------------
extern "C" void kernel_launch(void* const* d_in, const int* in_sizes, int n_in,
                              void* d_out, int out_size, void* d_ws, size_t ws_size,
                              hipStream_t stream) {
  (void)in_sizes; (void)n_in; (void)out_size; (void)ws_size;
  const float* x  = (const float*)d_in[0];
  const float* Wq = (const float*)d_in[1];
  const float* Wk = (const float*)d_in[2];
  const float* Wv = (const float*)d_in[3];
  const float* Wo = (const float*)d_in[4];
  float* out = (float*)d_out;

  char* ws = (char*)d_ws;
  const size_t WT = (size_t)CDIM * CDIM * sizeof(u16);   // 8 MiB
  const size_t QS = (size_t)MROWS * CDIM * sizeof(u16);  // 16 MiB
  u16* WqT = (u16*)(ws + 0 * WT);
  u16* WkT = (u16*)(ws + 1 * WT);
  u16* WvT = (u16*)(ws + 2 * WT);
  u16* WoT = (u16*)(ws + 3 * WT);
  u16* xb  = (u16*)(ws + 4 * WT);
  u16* qb  = (u16*)(ws + 4 * WT + 1 * QS);
  u16* kb  = (u16*)(ws + 4 * WT + 2 * QS);
  u16* vTb = (u16*)(ws + 4 * WT + 3 * QS);
  u16* ob  = (u16*)(ws + 4 * WT + 4 * QS);
  float* ct = (float*)(ws + 4 * WT + 5 * QS);
  float* st = ct + TSEQ * 64;

  transpose_kernel<<<dim3(64, 64, 5), dim3(32, 8), 0, stream>>>(
      Wq, Wk, Wv, Wo, WqT, WkT, WvT, WoT, x, xb);
  rope_table_kernel<<<dim3(TSEQ * 64 / 256), 256, 0, stream>>>(ct, st);
  gemm_bt_kernel<<<dim3(16, 3, 32), 256, 0, stream>>>(
      xb, WqT, WkT, WvT, qb, kb, vTb, 2, nullptr);
  rope_apply_kernel<<<dim3(16384, 2), 256, 0, stream>>>(qb, kb, ct, st);
  attn_kernel<<<dim3(16, 32), 512, 0, stream>>>(qb, kb, vTb, ob);
  gemm_bt_kernel<<<dim3(16, 1, 32), 256, 0, stream>>>(
      ob, WoT, WoT, WoT, nullptr, nullptr, nullptr, -1, out);
}

// Round 7
// 401.555 us; speedup vs baseline: 2.0146x; 1.0902x over previous
//
#include <hip/hip_runtime.h>

#define TSEQ   2048
#define CDIM   2048
#define NHEAD  16
#define DHEAD  128
#define NBATCH 2
#define MROWS  (NBATCH * TSEQ)   // 4096
#define WIN    512

typedef unsigned short u16;
typedef __attribute__((ext_vector_type(8))) short short8;   // 8 bf16 (4 VGPRs)
typedef __attribute__((ext_vector_type(4))) float f32x4;
typedef __attribute__((ext_vector_type(16))) float f32x16;
typedef __attribute__((ext_vector_type(4))) u16 u16x4;
typedef __attribute__((ext_vector_type(8))) u16 u16x8;

__device__ __forceinline__ void gload_lds16(const void* g, void* l) {
  __builtin_amdgcn_global_load_lds(
      (const __attribute__((address_space(1))) unsigned int*)g,
      (__attribute__((address_space(3))) unsigned int*)l, 16, 0, 0);
}

__device__ __forceinline__ u16 f2bf(float f) {
  unsigned u = __float_as_uint(f);
  u += 0x7fffu + ((u >> 16) & 1u);   // RNE
  return (u16)(u >> 16);
}
__device__ __forceinline__ float bf2f(u16 h) {
  return __uint_as_float((unsigned)h << 16);
}

// ---------------------------------------------------------------------------
// Weight transpose + fp32->bf16 (z<4): WT[n*C + k] = bf16(W[k*C + n]).
// z==4 plane: bulk convert x fp32 -> bf16 (2 float4 per thread).
// ---------------------------------------------------------------------------
__global__ __launch_bounds__(256) void transpose_kernel(
    const float* __restrict__ i0, const float* __restrict__ i1,
    const float* __restrict__ i2, const float* __restrict__ i3,
    u16* __restrict__ o0, u16* __restrict__ o1,
    u16* __restrict__ o2, u16* __restrict__ o3,
    const float* __restrict__ xin, u16* __restrict__ xout) {
  const int z = blockIdx.z;
  if (z == 4) {
    const int tf = threadIdx.y * 32 + threadIdx.x;
    const int base = (blockIdx.y * 64 + blockIdx.x) * 512 + tf * 2;
#pragma unroll
    for (int c = 0; c < 2; ++c) {
      const float4 v = ((const float4*)xin)[base + c];
      u16x4 ov;
      ov[0] = f2bf(v.x); ov[1] = f2bf(v.y); ov[2] = f2bf(v.z); ov[3] = f2bf(v.w);
      ((u16x4*)xout)[base + c] = ov;
    }
    return;
  }
  const float* in = (z == 0) ? i0 : (z == 1) ? i1 : (z == 2) ? i2 : i3;
  u16*       out = (z == 0) ? o0 : (z == 1) ? o1 : (z == 2) ? o2 : o3;
  __shared__ u16 tile[32][33];
  const int x  = blockIdx.x * 32 + threadIdx.x;
  const int y0 = blockIdx.y * 32 + threadIdx.y;
#pragma unroll
  for (int i = 0; i < 32; i += 8)
    tile[threadIdx.y + i][threadIdx.x] = f2bf(in[(size_t)(y0 + i) * CDIM + x]);
  __syncthreads();
  const int x2 = blockIdx.y * 32 + threadIdx.x;
  const int y2 = blockIdx.x * 32 + threadIdx.y;
#pragma unroll
  for (int i = 0; i < 32; i += 8)
    out[(size_t)(y2 + i) * CDIM + x2] = tile[threadIdx.x][threadIdx.y + i];
}

// ---------------------------------------------------------------------------
// RoPE tables: ct/st[t*64 + i] = cos/sin(t * 10000^(-i/64))
// ---------------------------------------------------------------------------
__global__ __launch_bounds__(256) void rope_table_kernel(float* __restrict__ ct,
                                                         float* __restrict__ st) {
  const int idx = blockIdx.x * 256 + threadIdx.x;   // < TSEQ*64
  const int t = idx >> 6, i = idx & 63;
  const float inv = exp2f(-(float)i * (13.287712379549449f / 64.0f)); // log2(10000)/64
  const float f = (float)t * inv;
  ct[idx] = cosf(f);
  st[idx] = sinf(f);
}

// ---------------------------------------------------------------------------
// RoPE apply, in place on q (y=0) / k (y=1). rotate-half pairs (i, i+64).
// ---------------------------------------------------------------------------
__global__ __launch_bounds__(256) void rope_apply_kernel(
    u16* __restrict__ q, u16* __restrict__ k,
    const float* __restrict__ ct, const float* __restrict__ st) {
  const int flat = blockIdx.x * 256 + threadIdx.x;  // < B*T*H*64 = 2^22
  u16* X = (blockIdx.y == 0) ? q : k;
  const int i = flat & 63;
  const int h = (flat >> 6) & (NHEAD - 1);
  const int t = (flat >> 10) & (TSEQ - 1);
  const int b = flat >> 21;
  const size_t base = ((size_t)(b * TSEQ + t)) * CDIM + h * DHEAD + i;
  const float u1 = bf2f(X[base]), u2 = bf2f(X[base + 64]);
  const float c = ct[t * 64 + i], s = st[t * 64 + i];
  X[base]      = f2bf(u1 * c - u2 * s);
  X[base + 64] = f2bf(u1 * s + u2 * c);
}

// ---------------------------------------------------------------------------
// BK=64 GEMM: C[M=4096, N=2048] = A[M,K=2048] * Bt[N,K]^T, bf16 internal.
// 128x128 tile, 4 waves, 16x16x32 MFMA, global_load_lds width 16.
// XOR-swizzled LDS layout. Grid (n, z, m).
// Epilogues: OF!=null -> fp32 natural; z==vz -> bf16 vT; else bf16 natural.
// ---------------------------------------------------------------------------
__global__ __launch_bounds__(256, 4) void gemm_bt_kernel(
    const u16* __restrict__ A,
    const u16* __restrict__ B0, const u16* __restrict__ B1, const u16* __restrict__ B2,
    u16* __restrict__ O0, u16* __restrict__ O1, u16* __restrict__ O2,
    int vz, float* __restrict__ OF) {
  const int z = blockIdx.y;
  const u16* Bt = (z == 0) ? B0 : (z == 1) ? B1 : B2;
  u16*       O  = (z == 0) ? O0 : (z == 1) ? O1 : O2;

  __shared__ u16 As[128 * 64];   // 16 KB, swizzled row-major
  __shared__ u16 Bs[128 * 64];   // 16 KB

  const int tid  = threadIdx.x;
  const int wave = tid >> 6;
  const int lane = tid & 63;
  const int quad = lane >> 4;
  const int l15  = lane & 15;

  const int bm = blockIdx.z * 128;
  const int bn = blockIdx.x * 128;

  const int rlo = lane >> 3;                     // 0..7
  const int swb = ((lane & 7) + rlo) & 7;        // swizzled source block
  const u16* Ag = A  + (size_t)(bm + wave * 32 + rlo) * CDIM + swb * 8;
  const u16* Bg = Bt + (size_t)(bn + wave * 32 + rlo) * CDIM + swb * 8;
  u16* AsW = As + wave * 2048 + lane * 8;
  u16* BsW = Bs + wave * 2048 + lane * 8;

  const f32x4 zero4 = {0.f, 0.f, 0.f, 0.f};
  f32x4 acc[4][4];
#pragma unroll
  for (int mt = 0; mt < 4; ++mt)
#pragma unroll
    for (int nt = 0; nt < 4; ++nt) acc[mt][nt] = zero4;

  const int mh = (wave >> 1) * 64;
  const int nh = (wave & 1) * 64;

  const int off0 = ((quad - l15) & 7) * 8;       // ks = 0
  const int off1 = off0 ^ 32;                    // ks = 1

  for (int kb = 0; kb < CDIM; kb += 64) {
#pragma unroll
    for (int g = 0; g < 4; ++g) {
      gload_lds16(Ag + kb + (size_t)g * 8 * CDIM, AsW + g * 512);
      gload_lds16(Bg + kb + (size_t)g * 8 * CDIM, BsW + g * 512);
    }
    __syncthreads();

#pragma unroll
    for (int ks = 0; ks < 2; ++ks) {
      const int fo = ks ? off1 : off0;
      short8 af[4], bfr[4];
#pragma unroll
      for (int t = 0; t < 4; ++t) {
        af[t]  = *(const short8*)(As + (mh + t * 16 + l15) * 64 + fo);
        bfr[t] = *(const short8*)(Bs + (nh + t * 16 + l15) * 64 + fo);
      }
#pragma unroll
      for (int mt = 0; mt < 4; ++mt)
#pragma unroll
        for (int nt = 0; nt < 4; ++nt)
          acc[mt][nt] = __builtin_amdgcn_mfma_f32_16x16x32_bf16(af[mt], bfr[nt],
                                                                acc[mt][nt], 0, 0, 0);
    }
    __syncthreads();
  }

  if (OF != nullptr) {
#pragma unroll
    for (int mt = 0; mt < 4; ++mt) {
      const int row0 = bm + mh + mt * 16 + quad * 4;
#pragma unroll
      for (int nt = 0; nt < 4; ++nt) {
        const int col = bn + nh + nt * 16 + l15;
#pragma unroll
        for (int r = 0; r < 4; ++r)
          OF[(size_t)(row0 + r) * CDIM + col] = acc[mt][nt][r];
      }
    }
  } else if (z != vz) {
#pragma unroll
    for (int mt = 0; mt < 4; ++mt) {
      const int row0 = bm + mh + mt * 16 + quad * 4;
#pragma unroll
      for (int nt = 0; nt < 4; ++nt) {
        const int col = bn + nh + nt * 16 + l15;
#pragma unroll
        for (int r = 0; r < 4; ++r)
          O[(size_t)(row0 + r) * CDIM + col] = f2bf(acc[mt][nt][r]);
      }
    }
  } else {
    // v epilogue: O = vT[(b*H + head)*D + d][t]; packed 8B store
    const int head = bn >> 7;
#pragma unroll
    for (int mt = 0; mt < 4; ++mt) {
      const int gm0 = bm + mh + mt * 16 + quad * 4;
      const int b  = gm0 >> 11;
      const int t0 = gm0 & (TSEQ - 1);
#pragma unroll
      for (int nt = 0; nt < 4; ++nt) {
        const int d = nh + nt * 16 + l15;
        u16x4 pk;
#pragma unroll
        for (int r = 0; r < 4; ++r) pk[r] = f2bf(acc[mt][nt][r]);
        *(u16x4*)(O + ((size_t)((b * NHEAD + head) * DHEAD + d)) * TSEQ + t0) = pk;
      }
    }
  }
}

// ---------------------------------------------------------------------------
// Flash attention, S^T formulation, 32x32x16 MFMA, in-register softmax.
// R7: surgical restore = R6 minus the d-split duplication. 256 threads,
// 4 waves, each wave owns one 32-row q-subtile with FULL d (oacc[4]);
// QK^T computed once per (q-subtile, tile); softmax once. Occupancy is
// grid-capped (512 blocks = 2 blocks/CU = 2 waves/SIMD), so no reg cap:
// __launch_bounds__(256,2) -> up to 256 regs, zero spill (R4/R5 lesson).
// Kept from R6 (all verified passing): XCD remap (K/V L2-resident, FETCH
// 25MB), linear LDS layout + XOR chunk swizzle with gload_lds staging via
// PRE-SWIZZLED global source (no staging regs, no writeT), in-register
// softmax (cvt_pk + permlane32_swap), tile-skip remap, depth-1 prefetch.
// LDS 32 KiB.
// ---------------------------------------------------------------------------
__global__ __launch_bounds__(256, 2) void attn_kernel(
    const u16* __restrict__ q, const u16* __restrict__ k,
    const u16* __restrict__ vT, u16* __restrict__ o) {
  __shared__ u16 ks[2 * 32 * 128];   // [buf][key 32][chan 128], chunk-swizzled
  __shared__ u16 vs[2 * 128 * 32];   // [buf][d 128][key 32], chunk-swizzled

  const int tid  = threadIdx.x;        // 0..255
  const int wave = tid >> 6;           // 0..3 = q-subtile
  const int lane = tid & 63;
  const int hi   = lane >> 5;          // k-half select in 32x32x16 fragments
  const int l31  = lane & 31;

  // XCD-aware remap: xcd = flat%8 owns 4 heads x 16 q-blocks
  // -> 4 MB K/V working set per XCD = one L2.
  const int flat = blockIdx.y * 16 + blockIdx.x;   // [0,512)
  const int qb   = (flat >> 3) & 15;
  const int bh   = (flat & 7) * 4 + (flat >> 7);   // b*16 + h
  const int b    = bh >> 4;
  const int h    = bh & 15;
  const int qw0  = qb * 128 + wave * 32;
  const int qi   = qw0 + l31;          // this lane's q row (col of S^T)

  // Q B-fragments: qf[s] = Q[qi][s*16 + hi*8 .. +8]
  short8 qf[8];
  {
    const u16* qrow = q + ((size_t)(b * TSEQ + qi)) * CDIM + h * DHEAD + hi * 8;
#pragma unroll
    for (int s = 0; s < 8; ++s) qf[s] = *(const short8*)(qrow + s * 16);
  }

  f32x16 oacc[4];   // [dt]: O^T[d = dt*32 + (r&3)+8*(r>>2)+4*hi][q = qi]
#pragma unroll
  for (int dt = 0; dt < 4; ++dt)
#pragma unroll
    for (int r = 0; r < 16; ++r) oacc[dt][r] = 0.f;
  float lrow = 0.f;

  const u16* kbase = k + ((size_t)(b * TSEQ)) * CDIM + h * DHEAD;
  const u16* vbase = vT + ((size_t)bh) * DHEAD * TSEQ;
  const float SC  = 0.08838834764831845f * 1.4426950408889634f; // 1/sqrt(128)*log2e
  const float MSH = 12.0f;   // fixed softmax shift (log2 domain)

  // remap out the fully-block-masked 32-key tiles: t in [4qb-12, 4qb-1]
  int tlo = 4 * qb - 12; if (tlo < 0) tlo = 0;
  int nskip = (4 * qb - 1) - tlo + 1; if (nskip < 0) nskip = 0;
  const int nact = 64 - nskip;   // 52..64
  auto jof = [&](int a) { return ((a < tlo) ? a : a + nskip) * 32; };

  // gload_lds staging, 4 waves x (2 K + 2 V) gloads per tile; LDS dest
  // linear (base + lane*16); global SOURCE pre-swizzled so that
  // LDS[row][c] = X[row][c ^ f(row)] (16B chunks), matching the reads.
  // K: wave w, issue g: rows w*8+g*4 + (l>>4), chunk l&15.
  const int kr0 = wave * 8 + (lane >> 4);
  const int kc  = lane & 15;
  const u16* kgp0 = kbase + (size_t)kr0 * CDIM + ((kc ^ (kr0 & 7)) * 8);
  const u16* kgp1 = kbase + (size_t)(kr0 + 4) * CDIM + ((kc ^ ((kr0 + 4) & 7)) * 8);
  // V: wave w, issue g: rows w*32+g*16 + (l>>2), chunk l&3.
  const int vr0 = wave * 32 + (lane >> 2);
  const int vc  = lane & 3;
  const u16* vgp0 = vbase + (size_t)vr0 * TSEQ + ((vc ^ ((vr0 >> 2) & 3)) * 8);
  const u16* vgp1 = vbase + (size_t)(vr0 + 16) * TSEQ + ((vc ^ (((vr0 + 16) >> 2) & 3)) * 8);
  u16* ksw0 = ks + (wave * 8) * 128 + lane * 8;        // buf0; buf1 = +4096
  u16* ksw1 = ks + (wave * 8 + 4) * 128 + lane * 8;
  u16* vsw0 = vs + (wave * 32) * 32 + lane * 8;
  u16* vsw1 = vs + (wave * 32 + 16) * 32 + lane * 8;

  auto stage = [&](int j, int buf) {
    const int off = buf * 4096;
    gload_lds16(kgp0 + (size_t)j * CDIM, ksw0 + off);
    gload_lds16(kgp1 + (size_t)j * CDIM, ksw1 + off);
    gload_lds16(vgp0 + j, vsw0 + off);
    gload_lds16(vgp1 + j, vsw1 + off);
  };

  // prologue: stage tile 0 into buffer 0
  stage(jof(0), 0);
  __syncthreads();

  for (int it = 0; it < nact; ++it) {
    const int p = it & 1;
    const int j0 = jof(it);

    // issue next tile's gloads into the other buffer (hidden under compute;
    // the barrier at loop end drains vmcnt before anyone reads it)
    if (it + 1 < nact) stage(jof(it + 1), 1 - p);

    const u16* ksp = ks + p * 4096;
    const u16* vsp = vs + p * 4096;

    const bool wskip = (j0 + 31 <= qw0) && (j0 >= qw0 + 31 - (WIN - 1));
    if (!wskip) {
      // S^T = K * Q^T: one 32x32 tile, K=128 over 8 MFMAs.
      f32x16 sf;
#pragma unroll
      for (int r = 0; r < 16; ++r) sf[r] = 0.f;
#pragma unroll
      for (int s = 0; s < 8; ++s) {
        const short8 kf =
            *(const short8*)(ksp + l31 * 128 + (((s * 2 + hi) ^ (l31 & 7)) * 8));
        sf = __builtin_amdgcn_mfma_f32_32x32x16_bf16(kf, qf[s], sf, 0, 0, 0);
      }

      // softmax numerator (+ mask only on band-edge tiles, wave-uniform).
      // element r: key = j0 + (r&3) + 8*(r>>2) + 4*hi, q = qi.
      float pe[16];
      const bool hasMask = (qw0 + 31 >= j0) && (qw0 <= j0 + 31 + (WIN - 1));
      if (hasMask) {
#pragma unroll
        for (int r = 0; r < 16; ++r) {
          const int kj = j0 + (r & 3) + 8 * (r >> 2) + 4 * hi;
          const float e = exp2f(fmaf(sf[r], SC, -MSH));
          pe[r] = ((unsigned)(qi - kj) < (unsigned)WIN) ? 0.f : e;
        }
      } else {
#pragma unroll
        for (int r = 0; r < 16; ++r) pe[r] = exp2f(fmaf(sf[r], SC, -MSH));
      }
#pragma unroll
      for (int r = 0; r < 16; ++r) lrow += pe[r];

      // P -> bf16 PV B-fragments, fully in registers:
      // 8x v_cvt_pk_bf16_f32 + 4x v_permlane32_swap_b32.
      int D0, D1, D2, D3, D4, D5, D6, D7;
      asm("v_cvt_pk_bf16_f32 %0, %1, %2" : "=v"(D0) : "v"(pe[0]),  "v"(pe[1]));
      asm("v_cvt_pk_bf16_f32 %0, %1, %2" : "=v"(D1) : "v"(pe[2]),  "v"(pe[3]));
      asm("v_cvt_pk_bf16_f32 %0, %1, %2" : "=v"(D2) : "v"(pe[4]),  "v"(pe[5]));
      asm("v_cvt_pk_bf16_f32 %0, %1, %2" : "=v"(D3) : "v"(pe[6]),  "v"(pe[7]));
      asm("v_cvt_pk_bf16_f32 %0, %1, %2" : "=v"(D4) : "v"(pe[8]),  "v"(pe[9]));
      asm("v_cvt_pk_bf16_f32 %0, %1, %2" : "=v"(D5) : "v"(pe[10]), "v"(pe[11]));
      asm("v_cvt_pk_bf16_f32 %0, %1, %2" : "=v"(D6) : "v"(pe[12]), "v"(pe[13]));
      asm("v_cvt_pk_bf16_f32 %0, %1, %2" : "=v"(D7) : "v"(pe[14]), "v"(pe[15]));
      asm("v_permlane32_swap_b32 %0, %1" : "+v"(D0), "+v"(D2));
      asm("v_permlane32_swap_b32 %0, %1" : "+v"(D1), "+v"(D3));
      asm("v_permlane32_swap_b32 %0, %1" : "+v"(D4), "+v"(D6));
      asm("v_permlane32_swap_b32 %0, %1" : "+v"(D5), "+v"(D7));

      union { int i[4]; short8 s8; } u0, u1;
      u0.i[0] = D0; u0.i[1] = D1; u0.i[2] = D2; u0.i[3] = D3;
      u1.i[0] = D4; u1.i[1] = D5; u1.i[2] = D6; u1.i[3] = D7;
      const short8 pf0 = u0.s8;   // B[k = keys 0..15][q]
      const short8 pf1 = u1.s8;   // B[k = keys 16..31][q]

      // O^T += V^T * P^T  (A = V^T rows d, 4 d-tiles x 2 k-steps)
#pragma unroll
      for (int dt = 0; dt < 4; ++dt) {
        const int row = dt * 32 + l31;
        const short8 vf0 =
            *(const short8*)(vsp + row * 32 + (((0 + hi) ^ ((l31 >> 2) & 3)) * 8));
        const short8 vf1 =
            *(const short8*)(vsp + row * 32 + (((2 + hi) ^ ((l31 >> 2) & 3)) * 8));
        oacc[dt] = __builtin_amdgcn_mfma_f32_32x32x16_bf16(vf0, pf0, oacc[dt], 0, 0, 0);
        oacc[dt] = __builtin_amdgcn_mfma_f32_32x32x16_bf16(vf1, pf1, oacc[dt], 0, 0, 0);
      }
    }

    __syncthreads();   // drains vmcnt (prefetch landed) + frees buf p
  }

  // lrow: lanes hi=0/1 hold complementary key subsets for the same q
  lrow += __shfl_xor(lrow, 32, 64);
  const float inv = 1.0f / lrow;

  // O^T[d][q]: reg r of tile dt -> d = dt*32 + 8*(r>>2) + 4*hi + (r&3)
  u16* obase = o + ((size_t)(b * TSEQ + qi)) * CDIM + h * DHEAD;
#pragma unroll
  for (int dt = 0; dt < 4; ++dt)
#pragma unroll
    for (int a2 = 0; a2 < 4; ++a2) {
      u16x4 pkd;
#pragma unroll
      for (int r = 0; r < 4; ++r) pkd[r] = f2bf(oacc[dt][a2 * 4 + r] * inv);
      *(u16x4*)(obase + dt * 32 + a2 * 8 + hi * 4) = pkd;
    }
}

// ---------------------------------------------------------------------------
extern "C" void kernel_launch(void* const* d_in, const int* in_sizes, int n_in,
                              void* d_out, int out_size, void* d_ws, size_t ws_size,
                              hipStream_t stream) {
  (void)in_sizes; (void)n_in; (void)out_size; (void)ws_size;
  const float* x  = (const float*)d_in[0];
  const float* Wq = (const float*)d_in[1];
  const float* Wk = (const float*)d_in[2];
  const float* Wv = (const float*)d_in[3];
  const float* Wo = (const float*)d_in[4];
  float* out = (float*)d_out;

  char* ws = (char*)d_ws;
  const size_t WT = (size_t)CDIM * CDIM * sizeof(u16);   // 8 MiB
  const size_t QS = (size_t)MROWS * CDIM * sizeof(u16);  // 16 MiB
  u16* WqT = (u16*)(ws + 0 * WT);
  u16* WkT = (u16*)(ws + 1 * WT);
  u16* WvT = (u16*)(ws + 2 * WT);
  u16* WoT = (u16*)(ws + 3 * WT);
  u16* xb  = (u16*)(ws + 4 * WT);
  u16* qb  = (u16*)(ws + 4 * WT + 1 * QS);
  u16* kb  = (u16*)(ws + 4 * WT + 2 * QS);
  u16* vTb = (u16*)(ws + 4 * WT + 3 * QS);
  u16* ob  = (u16*)(ws + 4 * WT + 4 * QS);
  float* ct = (float*)(ws + 4 * WT + 5 * QS);
  float* st = ct + TSEQ * 64;

  transpose_kernel<<<dim3(64, 64, 5), dim3(32, 8), 0, stream>>>(
      Wq, Wk, Wv, Wo, WqT, WkT, WvT, WoT, x, xb);
  rope_table_kernel<<<dim3(TSEQ * 64 / 256), 256, 0, stream>>>(ct, st);
  gemm_bt_kernel<<<dim3(16, 3, 32), 256, 0, stream>>>(
      xb, WqT, WkT, WvT, qb, kb, vTb, 2, nullptr);
  rope_apply_kernel<<<dim3(16384, 2), 256, 0, stream>>>(qb, kb, ct, st);
  attn_kernel<<<dim3(16, 32), 256, 0, stream>>>(qb, kb, vTb, ob);
  gemm_bt_kernel<<<dim3(16, 1, 32), 256, 0, stream>>>(
      ob, WoT, WoT, WoT, nullptr, nullptr, nullptr, -1, out);
}